// Round 9
// baseline (105.611 us; speedup 1.0000x reference)
//
#include <hip/hip_runtime.h>
#include <stdint.h>

// MinimumErrorRateLoss: unit-cost Levenshtein via Myers/Hyyrö bit-parallel DP.
// R9 = R8 with the outer-loop unroll REMOVED (unroll 1). R8's regression
// theory: unroll-3 of the ~300-instr phase body (~60 live VGPRs of pipeline
// state) caused spill/remat. Everything else identical to R8:
//  - u32 8-way word split, 256 blocks, 1024 waves (full chip, 1 wave/SIMD)
//  - R=8 DP steps per systolic phase, 39 phases
//  - 24-bit carry packet through ONE v_mov_dpp row_shr:1
//  - idempotent padding (PADTOK=1000, pm row 1000 = 0): no per-step
//    predication, no prefetch clamps. w=0 starts at base=0 (never pads);
//    w>=1 pad steps get hpin=0 from the chain and preserve (VP,VN)=(~0,0)
//    with zero carries out (induction up the word chain). Tail phases only
//    need the per-phase score guard.
//  - fused loss epilogue (1 block x 1024 threads).
//
// Layout (fixed problem size):
//   log_probs: (128, 64) f32      -> lp[b*64+s]
//   ref:       (256, 128) i32     -> ref[j*128+b]
//   hyp:       (256, 128, 64) i32 -> hyp[t*8192 + b*64 + s]
//   out:       scalar f32
// EOS = 0, INCLUDE_EOS -> len = first-EOS-idx + 1, else T.

#define BATCH   128
#define SAMPLES 64
#define RLEN    256
#define HLEN    256
#define NSEQ    (BATCH*SAMPLES)
#define NTOK    1000
#define PADTOK  1000       // pm has 1001 rows; row 1000 stays all-zero
#define SPB     32         // samples per block
#define PMSTR   9          // pm row stride in u32 (8 data + 1 pad)
#define HEADPAD 56         // pad tokens before t=0   (covers base >= -56)
#define HTROW   392        // 56 + 256 + 80 pad u16; 784 B row (16-B aligned)
#define RSTEP   8          // DP steps per systolic phase
#define NPH     39         // 256/8 + 8 - 1

typedef unsigned long long u64;
typedef unsigned int       u32;

// DPP row_shr:1 -> lane i reads lane i-1 within rows of 16; row-lane-0 gets 0.
__device__ __forceinline__ int row_shr1(int x) {
    return __builtin_amdgcn_mov_dpp(x, 0x111, 0xf, 0xf, true);
}

__global__ __launch_bounds__(256) void mer_edit(const int* __restrict__ ref,
                                                const int* __restrict__ hyp,
                                                int* __restrict__ scores,
                                                int* __restrict__ reflen)
{
    const int blk  = blockIdx.x;      // 0..255
    const int b    = blk >> 1;        // batch element
    const int half = blk & 1;         // sample half (0: s 0..31, 1: s 32..63)
    const int tid  = threadIdx.x;     // 0..255
    const int w    = tid & 7;         // u32 word 0..7
    const int sl   = tid >> 3;        // local sample 0..31

    __shared__ __align__(16) u32 pm[9012];                   // 1001*9=9009 (+pad)
    __shared__ __align__(16) unsigned short ht[SPB * HTROW]; // 25088 B
    __shared__ int m_sh;

    if (tid == 0) m_sh = RLEN;

    // ---- zero PM (9012 u32 = 2253 int4) ----
    for (int i = tid; i < 2253; i += 256)
        ((int4*)pm)[i] = int4{0, 0, 0, 0};

    // ---- fill ht pad columns with PADTOK (disjoint from transpose region) ----
    {
        const int r = tid >> 3, c = tid & 7;       // row 0..31, chunk 0..7
        u32* rowp = (u32*)ht + r * (HTROW / 2);    // 196 u32 per row
#pragma unroll
        for (int j0 = 0; j0 < 9; ++j0) {
            int j = c * 9 + j0;                    // 0..71; need 0..67
            if (j < 68) {
                int off = (j < 28) ? j : (156 + (j - 28)); // head 0..27, tail 156..195
                rowp[off] = 0x03E803E8u;           // PADTOK | PADTOK<<16
            }
        }
    }

    // ---- stage hyp slab TRANSPOSED: ht[s][HEADPAD + t], int4 loads ----
#pragma unroll
    for (int it = 0; it < 8; it++) {
        int idx = it * 256 + tid;     // int4 index
        int t   = idx >> 3;           // 0..255
        int s4  = (idx & 7) * 4;      // 0,4,..,28
        int4 v  = *(const int4*)(hyp + t * NSEQ + b * SAMPLES + half * SPB + s4);
        ht[(s4 + 0) * HTROW + HEADPAD + t] = (unsigned short)v.x;
        ht[(s4 + 1) * HTROW + HEADPAD + t] = (unsigned short)v.y;
        ht[(s4 + 2) * HTROW + HEADPAD + t] = (unsigned short)v.z;
        ht[(s4 + 3) * HTROW + HEADPAD + t] = (unsigned short)v.w;
    }

    // ---- ref column: one token per thread (j = tid) ----
    const int rt = ref[tid * BATCH + b];
    __syncthreads();                  // m_sh + pm zero done
    if (rt == 0) atomicMin(&m_sh, tid);
    __syncthreads();
    const int m = (m_sh < RLEN) ? (m_sh + 1) : RLEN;   // ref_len, 1..256
    if (tid < m)
        atomicOr(&pm[rt * PMSTR + (tid >> 5)], 1u << (tid & 31));
    __syncthreads();                  // pm + ht ready; no more barriers

    // ---- systolic-in-wave Myers, u32 words, 8 steps/phase ----
    const int  sw   = (m - 1) >> 5, sb = (m - 1) & 31;  // score bit location
    const bool isW0 = (w == 0);
    const bool isSW = (w == sw);
    const u32* pmw  = pm + w;
    const unsigned short* htrow = ht + sl * HTROW + HEADPAD;

    u32  VP = ~0u, VN = 0u;
    int  score = m;
    bool done  = false;
    int  base  = -(w << 3);           // this phase's first DP step

    // prime: current tokens (a0..a7) + their Eq; next-phase packed tokens tkB
    uint4 tkB;
    u32 a0,a1,a2,a3,a4,a5,a6,a7;
    u32 eqA0,eqA1,eqA2,eqA3,eqA4,eqA5,eqA6,eqA7;
    {
        uint4 tkA = *(const uint4*)(htrow + base);       // base >= -56: in pads
        tkB = *(const uint4*)(htrow + base + 8);
        a0 = tkA.x & 0xFFFFu; a1 = tkA.x >> 16;
        a2 = tkA.y & 0xFFFFu; a3 = tkA.y >> 16;
        a4 = tkA.z & 0xFFFFu; a5 = tkA.z >> 16;
        a6 = tkA.w & 0xFFFFu; a7 = tkA.w >> 16;
        eqA0 = pmw[a0 * PMSTR]; eqA1 = pmw[a1 * PMSTR];
        eqA2 = pmw[a2 * PMSTR]; eqA3 = pmw[a3 * PMSTR];
        eqA4 = pmw[a4 * PMSTR]; eqA5 = pmw[a5 * PMSTR];
        eqA6 = pmw[a6 * PMSTR]; eqA7 = pmw[a7 * PMSTR];
    }

    int out_pkd = 0;   // 24-bit carry packet from my previous phase

#define STEP(EQ, TK, I) do {                                              \
        u32 cin  = ((u32)inp >> (I)) & 1u;                                \
        u32 hpin = ((u32)inp >> (8 + (I))) & 1u;                          \
        u32 hnin = ((u32)inp >> (16 + (I))) & 1u;                         \
        u32 x  = (EQ) & VP;                                               \
        u64 S  = (u64)x + VP + cin;                                       \
        u32 s2 = (u32)S;                                                  \
        u32 D0 = (s2 ^ VP) | (EQ) | VN;                                   \
        u32 HP = VN | ~(D0 | VP);                                         \
        u32 HN = VP & D0;                                                 \
        nout |= ((u32)(S >> 32) << (I)) | ((HP >> 31) << (8 + (I)))       \
                | ((HN >> 31) << (16 + (I)));                             \
        int delta = (int)((HP >> sb) & 1u) - (int)((HN >> sb) & 1u);      \
        u32 HPs = (HP << 1) | hpin;                                       \
        u32 HNs = (HN << 1) | hnin;                                       \
        VP = HNs | ~(D0 | HPs);                                           \
        VN = HPs & D0;                                                    \
        if (pvalid && !done) score += delta;                              \
        done = done | ((TK) == 0);    /* pads are 1000, never EOS */      \
    } while (0)

#pragma unroll 1
    for (int P = 0; P < NPH; ++P) {
        // token prefetch for phase P+2 (pads guarantee in-bounds, no clamps)
        uint4 tkC = *(const uint4*)(htrow + base + 16);

        // Eq loads for phase P+1 tokens (tkB)
        u32 n0 = tkB.x & 0xFFFFu, n1 = tkB.x >> 16;
        u32 n2 = tkB.y & 0xFFFFu, n3 = tkB.y >> 16;
        u32 n4 = tkB.z & 0xFFFFu, n5 = tkB.z >> 16;
        u32 n6 = tkB.w & 0xFFFFu, n7 = tkB.w >> 16;
        u32 eqB0 = pmw[n0 * PMSTR], eqB1 = pmw[n1 * PMSTR];
        u32 eqB2 = pmw[n2 * PMSTR], eqB3 = pmw[n3 * PMSTR];
        u32 eqB4 = pmw[n4 * PMSTR], eqB5 = pmw[n5 * PMSTR];
        u32 eqB6 = pmw[n6 * PMSTR], eqB7 = pmw[n7 * PMSTR];

        // carry packet from word w-1 (its previous phase), one DPP
        int inp = row_shr1(out_pkd);
        if (isW0) inp = 0xFF00;       // cin=0, hpin=1 (D[0][j]=j), hnin=0 x8

        const bool pvalid = ((u32)base < (u32)HLEN);   // tail guard only
        u32 nout = 0;
        STEP(eqA0, a0, 0);
        STEP(eqA1, a1, 1);
        STEP(eqA2, a2, 2);
        STEP(eqA3, a3, 3);
        STEP(eqA4, a4, 4);
        STEP(eqA5, a5, 5);
        STEP(eqA6, a6, 6);
        STEP(eqA7, a7, 7);
        out_pkd = (int)nout;

        // rotate pipeline
        a0 = n0; a1 = n1; a2 = n2; a3 = n3;
        a4 = n4; a5 = n5; a6 = n6; a7 = n7;
        eqA0 = eqB0; eqA1 = eqB1; eqA2 = eqB2; eqA3 = eqB3;
        eqA4 = eqB4; eqA5 = eqB5; eqA6 = eqB6; eqA7 = eqB7;
        tkB = tkC;
        base += RSTEP;
    }
#undef STEP

    if (isSW) scores[b * SAMPLES + half * SPB + sl] = score;
    if (half == 0 && tid == 0) reflen[b] = m;
}

// Single block, 1024 threads = 16 waves; wave wv handles batches wv*8..wv*8+7.
//   per-batch: sum_s (er - mean_er)*softmax = dot(er,p)/sumexp - mean_er
__global__ __launch_bounds__(1024) void mer_tail(const float* __restrict__ lp,
                                                 const int* __restrict__ scores,
                                                 const int* __restrict__ reflen,
                                                 float* __restrict__ out)
{
    const int tid = threadIdx.x;
    const int s   = tid & 63;
    const int wv  = tid >> 6;         // 0..15
    __shared__ double red[16];

    double acc = 0.0;
#pragma unroll
    for (int k = 0; k < 8; k++) {
        const int b  = wv * 8 + k;
        double er = (double)scores[b * SAMPLES + s] / (double)reflen[b];
        double x  = (double)lp[b * SAMPLES + s];
        double mx = x;
#pragma unroll
        for (int off = 32; off > 0; off >>= 1)
            mx = fmax(mx, __shfl_xor(mx, off));
        double e = exp(x - mx);
        double se = e, see = er * e, ser = er;
#pragma unroll
        for (int off = 32; off > 0; off >>= 1) {
            se  += __shfl_xor(se,  off);
            see += __shfl_xor(see, off);
            ser += __shfl_xor(ser, off);
        }
        if (s == 0) acc += see / se - ser * (1.0 / SAMPLES);
    }
    if (s == 0) red[wv] = acc;
    __syncthreads();
    if (tid == 0) {
        double v = 0.0;
#pragma unroll
        for (int i = 0; i < 16; i++) v += red[i];
        out[0] = (float)(v / (double)(BATCH * SAMPLES));
    }
}

extern "C" void kernel_launch(void* const* d_in, const int* in_sizes, int n_in,
                              void* d_out, int out_size, void* d_ws, size_t ws_size,
                              hipStream_t stream)
{
    const float* lp  = (const float*)d_in[0];
    const int*   ref = (const int*)d_in[1];
    const int*   hyp = (const int*)d_in[2];

    int*   scores = (int*)d_ws;                  // 8192 i32
    int*   reflen = scores + NSEQ;               // 128 i32
    float* out    = (float*)d_out;

    mer_edit<<<2 * BATCH, 256, 0, stream>>>(ref, hyp, scores, reflen);
    mer_tail<<<1, 1024, 0, stream>>>(lp, scores, reflen, out);
}

// Round 10
// 90.019 us; speedup vs baseline: 1.1732x; 1.1732x over previous
//
#include <hip/hip_runtime.h>
#include <stdint.h>

// MinimumErrorRateLoss: unit-cost Levenshtein via Myers/Hyyrö bit-parallel DP.
// R10 = R7 (proven 92.6 µs: u32 8-way word split, R=4 steps/phase, 72 phases,
// unroll 2, separate loss kernels) + idempotent padding ONLY (verified piece
// of the R8 bundle; R=8 itself regressed and is dropped):
//   hyp rows staged transposed with 28 head / 40 tail PADTOK(=1000) tokens,
//   pm row 1000 == 0. Pad steps (Eq=0, zero chain inputs) preserve
//   (VP,VN)=(~0,0) and emit zero carries (induction up the word chain; w=0
//   never executes pad steps since base starts at 0). So: NO per-step VP/VN
//   predication, NO prefetch clamps; only the per-phase score guard remains
//   (phases align to 4-step boundaries: base % 4 == 0, HLEN % 4 == 0).
//
// Layout (fixed problem size):
//   log_probs: (128, 64) f32      -> lp[b*64+s]
//   ref:       (256, 128) i32     -> ref[j*128+b]   (shared across samples)
//   hyp:       (256, 128, 64) i32 -> hyp[t*8192 + b*64 + s]
//   out:       scalar f32
// EOS = 0, INCLUDE_EOS -> len = first-EOS-idx + 1, else T.

#define BATCH   128
#define SAMPLES 64
#define RLEN    256
#define HLEN    256
#define NSEQ    (BATCH*SAMPLES)
#define NTOK    1000
#define PADTOK  1000       // pm has 1001 rows; row 1000 stays all-zero
#define SPB     32         // samples per block
#define PMSTR   9          // pm row stride in u32 (8 data + 1 pad)
#define HEADPAD 28         // pad tokens before t=0 (covers base >= -28)
#define TAILPAD 40         // pad tokens after t=255 (covers reads to 295)
#define HTROW   324        // 28 + 256 + 40 u16 = 648 B/row (8-B aligned)
#define RSTEP   4          // DP steps per systolic phase
#define NPH     72         // 256/4 + 8 - 1 = 71, +1 (even, for unroll 2)

typedef unsigned long long u64;
typedef unsigned int       u32;

// DPP row_shr:1 -> lane i reads lane i-1 within rows of 16; row-lane-0 gets 0.
__device__ __forceinline__ int row_shr1(int x) {
    return __builtin_amdgcn_mov_dpp(x, 0x111, 0xf, 0xf, true);
}

__global__ __launch_bounds__(256) void mer_edit(const int* __restrict__ ref,
                                                const int* __restrict__ hyp,
                                                int* __restrict__ scores,
                                                int* __restrict__ reflen)
{
    const int blk  = blockIdx.x;      // 0..255
    const int b    = blk >> 1;        // batch element
    const int half = blk & 1;         // sample half (0: s 0..31, 1: s 32..63)
    const int tid  = threadIdx.x;     // 0..255
    const int w    = tid & 7;         // u32 word 0..7
    const int sl   = tid >> 3;        // local sample 0..31

    __shared__ __align__(16) u32 pm[9012];                   // 1001*9=9009 (+pad)
    __shared__ __align__(8)  unsigned short ht[SPB * HTROW]; // 20736 B
    __shared__ int m_sh;

    if (tid == 0) m_sh = RLEN;

    // ---- zero PM (9012 u32 = 2253 int4) ----
    for (int i = tid; i < 2253; i += 256)
        ((int4*)pm)[i] = int4{0, 0, 0, 0};

    // ---- fill ht pad regions with PADTOK ----
    // row = 162 u32: head u32 [0,14), data [14,142), tail [142,162) -> 34 pads
    {
        const int r = tid >> 3, c = tid & 7;       // row 0..31, chunk 0..7
        u32* rowp = (u32*)ht + r * (HTROW / 2);
#pragma unroll
        for (int j0 = 0; j0 < 5; ++j0) {
            int j = c * 5 + j0;                    // 0..39; need 0..33
            if (j < 34) {
                int off = (j < 14) ? j : (142 + (j - 14));
                rowp[off] = 0x03E803E8u;           // PADTOK | PADTOK<<16
            }
        }
    }

    // ---- stage hyp slab TRANSPOSED: ht[s][HEADPAD + t], int4 loads ----
#pragma unroll
    for (int it = 0; it < 8; it++) {
        int idx = it * 256 + tid;     // int4 index
        int t   = idx >> 3;           // 0..255
        int s4  = (idx & 7) * 4;      // 0,4,..,28
        int4 v  = *(const int4*)(hyp + t * NSEQ + b * SAMPLES + half * SPB + s4);
        ht[(s4 + 0) * HTROW + HEADPAD + t] = (unsigned short)v.x;
        ht[(s4 + 1) * HTROW + HEADPAD + t] = (unsigned short)v.y;
        ht[(s4 + 2) * HTROW + HEADPAD + t] = (unsigned short)v.z;
        ht[(s4 + 3) * HTROW + HEADPAD + t] = (unsigned short)v.w;
    }

    // ---- ref column: one token per thread (j = tid) ----
    const int rt = ref[tid * BATCH + b];
    __syncthreads();                  // m_sh + pm zero done
    if (rt == 0) atomicMin(&m_sh, tid);
    __syncthreads();
    const int m = (m_sh < RLEN) ? (m_sh + 1) : RLEN;   // ref_len, 1..256
    if (tid < m)
        atomicOr(&pm[rt * PMSTR + (tid >> 5)], 1u << (tid & 31));
    __syncthreads();                  // pm + ht ready; no more barriers

    // ---- systolic-in-wave Myers, u32 words, 4 steps/phase ----
    const int  sw   = (m - 1) >> 5, sb = (m - 1) & 31;  // score bit location
    const bool isW0 = (w == 0);
    const bool isSW = (w == sw);
    const u32* pmw  = pm + w;
    const unsigned short* htrow = ht + sl * HTROW + HEADPAD;

    u32  VP = ~0u, VN = 0u;
    int  score = m;
    bool done  = false;
    int  base  = -(w << 2);           // this phase's first DP step (mult of 4)

    // prime: tokens for phase 0 and 1 (pads make all reads in-bounds)
    uint2 tkA = *(const uint2*)(htrow + base);       // 4 u16 tokens, phase P
    uint2 tkB = *(const uint2*)(htrow + base + 4);   // phase P+1
    u32 eqA0, eqA1, eqA2, eqA3;
    {
        u32 p0 = tkA.x & 0xFFFFu, p1 = tkA.x >> 16;
        u32 p2 = tkA.y & 0xFFFFu, p3 = tkA.y >> 16;
        eqA0 = pmw[p0 * PMSTR]; eqA1 = pmw[p1 * PMSTR];
        eqA2 = pmw[p2 * PMSTR]; eqA3 = pmw[p3 * PMSTR];
    }

    int out_pkd = 0;   // 12-bit carry packet from my previous phase

#define STEP(EQ, TK, I) do {                                              \
        u32 cin  = ((u32)inp >> (I)) & 1u;                                \
        u32 hpin = ((u32)inp >> (8 + (I))) & 1u;                          \
        u32 hnin = ((u32)inp >> (16 + (I))) & 1u;                         \
        u32 x  = (EQ) & VP;                                               \
        u64 S  = (u64)x + VP + cin;                                       \
        u32 s2 = (u32)S;                                                  \
        u32 D0 = (s2 ^ VP) | (EQ) | VN;                                   \
        u32 HP = VN | ~(D0 | VP);                                         \
        u32 HN = VP & D0;                                                 \
        nout |= ((u32)(S >> 32) << (I)) | ((HP >> 31) << (8 + (I)))       \
                | ((HN >> 31) << (16 + (I)));                             \
        int delta = (int)((HP >> sb) & 1u) - (int)((HN >> sb) & 1u);      \
        u32 HPs = (HP << 1) | hpin;                                       \
        u32 HNs = (HN << 1) | hnin;                                       \
        VP = HNs | ~(D0 | HPs);                                           \
        VN = HPs & D0;                                                    \
        if (pvalid && !done) score += delta;                              \
        done = done | ((TK) == 0);    /* pads are 1000, never EOS */      \
    } while (0)

#pragma unroll 2
    for (int P = 0; P < NPH; ++P) {
        // token prefetch for phase P+2 (pads guarantee in-bounds, no clamps)
        uint2 tkC = *(const uint2*)(htrow + base + 8);

        // Eq loads for phase P+1 tokens (tkB, loaded last phase)
        u32 n0 = tkB.x & 0xFFFFu, n1 = tkB.x >> 16;
        u32 n2 = tkB.y & 0xFFFFu, n3 = tkB.y >> 16;
        u32 eqB0 = pmw[n0 * PMSTR], eqB1 = pmw[n1 * PMSTR];
        u32 eqB2 = pmw[n2 * PMSTR], eqB3 = pmw[n3 * PMSTR];

        // carry packet from word w-1 (its previous phase), one DPP
        int inp = row_shr1(out_pkd);
        if (isW0) inp = 0x0F00;       // cin=0, hpin=1 (D[0][j]=j), hnin=0 x4

        const bool pvalid = ((u32)base < (u32)HLEN);   // whole phase in range
        u32 nout = 0;
        u32 a0 = tkA.x & 0xFFFFu, a1 = tkA.x >> 16;
        u32 a2 = tkA.y & 0xFFFFu, a3 = tkA.y >> 16;
        STEP(eqA0, a0, 0);
        STEP(eqA1, a1, 1);
        STEP(eqA2, a2, 2);
        STEP(eqA3, a3, 3);
        out_pkd = (int)nout;

        // rotate pipeline
        tkA = tkB; tkB = tkC;
        eqA0 = eqB0; eqA1 = eqB1; eqA2 = eqB2; eqA3 = eqB3;
        base += RSTEP;
    }
#undef STEP

    if (isSW) scores[b * SAMPLES + half * SPB + sl] = score;
    if (half == 0 && tid == 0) reflen[b] = m;
}

// Grid 128 x 64 threads: per-batch f64 loss partial.
//   sum_s (er - mean_er)*softmax = dot(er,p)/sumexp - mean_er  (sum p = 1)
__global__ __launch_bounds__(64) void mer_loss(const float* __restrict__ lp,
                                               const int* __restrict__ scores,
                                               const int* __restrict__ reflen,
                                               double* __restrict__ partial)
{
    const int b = blockIdx.x, s = threadIdx.x;
    double er = (double)scores[b * SAMPLES + s] / (double)reflen[b];
    double x  = (double)lp[b * SAMPLES + s];
    double mx = x;
#pragma unroll
    for (int off = 32; off > 0; off >>= 1)
        mx = fmax(mx, __shfl_xor(mx, off));
    double e = exp(x - mx);
    double se = e, see = er * e, ser = er;
#pragma unroll
    for (int off = 32; off > 0; off >>= 1) {
        se  += __shfl_xor(se,  off);
        see += __shfl_xor(see, off);
        ser += __shfl_xor(ser, off);
    }
    if (s == 0) partial[b] = see / se - ser * (1.0 / SAMPLES);
}

// 1 block, 64 threads: sum 128 per-batch partials, scale, write scalar.
__global__ __launch_bounds__(64) void mer_final(const double* __restrict__ partial,
                                                float* __restrict__ out)
{
    const int tid = threadIdx.x;
    double v = partial[tid] + partial[tid + 64];
#pragma unroll
    for (int off = 32; off > 0; off >>= 1)
        v += __shfl_xor(v, off);
    if (tid == 0) out[0] = (float)(v / (double)(BATCH * SAMPLES));
}

extern "C" void kernel_launch(void* const* d_in, const int* in_sizes, int n_in,
                              void* d_out, int out_size, void* d_ws, size_t ws_size,
                              hipStream_t stream)
{
    const float* lp  = (const float*)d_in[0];
    const int*   ref = (const int*)d_in[1];
    const int*   hyp = (const int*)d_in[2];

    double* partial = (double*)d_ws;                   // 128 f64
    int*    scores  = (int*)(partial + BATCH);         // 8192 i32
    int*    reflen  = scores + NSEQ;                   // 128 i32
    float*  out     = (float*)d_out;

    mer_edit<<<2 * BATCH, 256, 0, stream>>>(ref, hyp, scores, reflen);
    mer_loss<<<BATCH, 64, 0, stream>>>(lp, scores, reflen, partial);
    mer_final<<<1, 64, 0, stream>>>(partial, out);
}